// Round 3
// baseline (233.216 us; speedup 1.0000x reference)
//
#include <hip/hip_runtime.h>

// 3-level separable 2D DWT, bior3.5, mode='periodization'.
// out[i] = sum_j f[j] * x[(2i+1-j) mod N] along each axis.
// v3: no input staging tile (row pass reads global float4 directly; L1/L2 serve
//     the overlap), transposed lo/hi in LDS with stride 42 (conflict-free b32
//     writes + b64 reads), single barrier, kernel templated on N.

#define OW 32
#define OH 16
#define IN_ROWS (2 * OH + 10)   // 42 staged filter rows
#define TRS 42                  // transposed stride (floats); 42%32=10 -> conflict-free

template <int N>
__global__ __launch_bounds__(256, 8) void dwt2_level(
    const float* __restrict__ src,
    float* __restrict__ aa, float* __restrict__ da,
    float* __restrict__ ad, float* __restrict__ dd)
{
    constexpr float SQ2 = 1.41421356237309504880f;
    constexpr float c_lo[12] = {
        -20.f * SQ2 / 2048.f,  60.f * SQ2 / 2048.f,   76.f * SQ2 / 2048.f,
        -388.f * SQ2 / 2048.f, -104.f * SQ2 / 2048.f, 1400.f * SQ2 / 2048.f,
        1400.f * SQ2 / 2048.f, -104.f * SQ2 / 2048.f, -388.f * SQ2 / 2048.f,
        76.f * SQ2 / 2048.f,   60.f * SQ2 / 2048.f,   -20.f * SQ2 / 2048.f };
    // dec_hi nonzero taps (jc = 4..7)
    constexpr float c_hi4[4] = { -SQ2 / 8.f, 3.f * SQ2 / 8.f, -3.f * SQ2 / 8.f, SQ2 / 8.f };

    constexpr int h    = N >> 1;
    constexpr int mask = N - 1;

    const int bc  = blockIdx.z;
    const int j0  = blockIdx.x * OW;   // output col base
    const int i0  = blockIdx.y * OH;   // output row base
    const int tid = threadIdx.x;       // 0..255

    __shared__ float s_loT[OW][TRS];   // [out col][filter row]  5.25 KB
    __shared__ float s_hiT[OW][TRS];   // 5.25 KB -> 8 blocks/CU (wave-capped)

    const float* img = src + (unsigned)bc * (unsigned)(N * N);
    const int r0 = 2 * i0 - 10;        // first filter row (may be <0, wrap)
    const int c0 = 2 * j0 - 12;        // 16B-aligned col base

    // ---- Phase A: row pass straight from global. Task = (row r, col-quad m):
    // computes output cols 4m..4m+3 from the 20-float window [c0+8m, c0+8m+19].
    for (int t = tid; t < IN_ROWS * (OW / 4); t += 256) {
        const int m = t & (OW / 4 - 1);   // 0..7
        const int r = t >> 3;             // 0..41
        const int gr = (r0 + r) & mask;
        const float* row = img + (unsigned)(gr * N);
        const int cb = c0 + 8 * m;
        float v[20];
        if (cb >= 0) {                    // interior (always true unless blockIdx.x==0, m<2)
            #pragma unroll
            for (int q = 0; q < 5; ++q)
                *(float4*)&v[4 * q] = *(const float4*)&row[cb + 4 * q];
        } else {                          // left-edge wrap
            #pragma unroll
            for (int k = 0; k < 20; ++k)
                v[k] = row[(cb + k) & mask];
        }
        #pragma unroll
        for (int d = 0; d < 4; ++d) {
            float lo = 0.f, hi = 0.f;
            #pragma unroll
            for (int jc = 0; jc < 12; ++jc)
                lo += c_lo[jc] * v[2 * d + 13 - jc];
            #pragma unroll
            for (int k = 0; k < 4; ++k)
                hi += c_hi4[k] * v[2 * d + 9 - k];
            s_loT[4 * m + d][r] = lo;
            s_hiT[4 * m + d][r] = hi;
        }
    }
    __syncthreads();

    // ---- Phase B: column pass. Thread (tx, ty) -> col j0+tx, rows i0+2ty, i0+2ty+1.
    const int tx = tid & 31;
    const int ty = tid >> 5;              // 0..7
    float l[14], hh[14];
    #pragma unroll
    for (int e = 0; e < 7; ++e) {         // b64 reads, conflict-free at stride 42
        *(float2*)&l[2 * e]  = *(const float2*)&s_loT[tx][4 * ty + 2 * e];
        *(float2*)&hh[2 * e] = *(const float2*)&s_hiT[tx][4 * ty + 2 * e];
    }
    float vaa0 = 0.f, vaa1 = 0.f, vad0 = 0.f, vad1 = 0.f;
    #pragma unroll
    for (int jr = 0; jr < 12; ++jr) {
        vaa0 += c_lo[jr] * l[11 - jr];
        vaa1 += c_lo[jr] * l[13 - jr];
        vad0 += c_lo[jr] * hh[11 - jr];
        vad1 += c_lo[jr] * hh[13 - jr];
    }
    float vda0 = 0.f, vda1 = 0.f, vdd0 = 0.f, vdd1 = 0.f;
    #pragma unroll
    for (int k = 0; k < 4; ++k) {
        vda0 += c_hi4[k] * l[7 - k];
        vda1 += c_hi4[k] * l[9 - k];
        vdd0 += c_hi4[k] * hh[7 - k];
        vdd1 += c_hi4[k] * hh[9 - k];
    }
    const unsigned ob = (unsigned)((bc * h + i0 + 2 * ty) * h + j0 + tx);
    aa[ob] = vaa0;  aa[ob + h] = vaa1;
    da[ob] = vda0;  da[ob + h] = vda1;
    ad[ob] = vad0;  ad[ob + h] = vad1;
    dd[ob] = vdd0;  dd[ob + h] = vdd1;
}

extern "C" void kernel_launch(void* const* d_in, const int* in_sizes, int n_in,
                              void* d_out, int out_size, void* d_ws, size_t ws_size,
                              hipStream_t stream) {
    const float* x = (const float*)d_in[0];
    float* out = (float*)d_out;
    float* ws  = (float*)d_ws;

    // 24 independent N x N images (8 batch x 3 channels).
    const size_t s512 = (size_t)24 * 512 * 512;  // 6291456
    const size_t s256 = (size_t)24 * 256 * 256;  // 1572864
    const size_t s128 = (size_t)24 * 128 * 128;  //  393216

    // d_out layout (return order): a | h3(da,ad,dd) | h2(...) | h1(...)
    float* a_out = out;
    float* h3 = out + s128;
    float* h2 = out + 4 * s128;
    float* h1 = out + 4 * s128 + 3 * s256;

    // scratch: aa after level 1 (512^2) and level 2 (256^2)
    float* aa1 = ws;          // s512 floats
    float* aa2 = ws + s512;   // s256 floats
    (void)in_sizes; (void)n_in; (void)out_size; (void)ws_size;

    dim3 blk(256, 1, 1);
    // level 1: 1024 -> 512
    dwt2_level<1024><<<dim3(512 / OW, 512 / OH, 24), blk, 0, stream>>>(
        x, aa1, h1, h1 + s512, h1 + 2 * s512);
    // level 2: 512 -> 256
    dwt2_level<512><<<dim3(256 / OW, 256 / OH, 24), blk, 0, stream>>>(
        aa1, aa2, h2, h2 + s256, h2 + 2 * s256);
    // level 3: 256 -> 128
    dwt2_level<256><<<dim3(128 / OW, 128 / OH, 24), blk, 0, stream>>>(
        aa2, a_out, h3, h3 + s128, h3 + 2 * s128);
}

// Round 4
// 76.060 us; speedup vs baseline: 3.0662x; 3.0662x over previous
//
#include <hip/hip_runtime.h>

// 3-level separable 2D DWT, bior3.5, mode='periodization'.
// out[i] = sum_j f[j] * x[(2i+1-j) mod N] along each axis.
// v4: register-prefetch pipeline (T14): per block, NSTEP=4 steps of a 32x16
//     output tile; next step's input quads are loaded into registers while the
//     current step computes, then ds_written after the mid-step barrier.
//     All staged loads are contiguous 16B (wrap collapses to masked quad base).
//     Bank-uniform LDS layouts: s_in pitch 84, transposed pitch 42.

#define OW 32                  // output cols per block
#define OHS 16                 // output rows per step
#define NSTEP 4                // steps per block -> 64 output rows per block
#define ROWS_PB (OHS * NSTEP)
#define IN_ROWS 42             // 2*OHS + 10 staged input rows per step
#define QPR 20                 // float4 quads per staged row (80 cols)
#define NQ (IN_ROWS * QPR)     // 840 staged quads per step
#define SPITCH 84              // s_in dword pitch (80 data + 4 pad: uniform b128 banks)
#define TRS 42                 // transposed pitch (2-way-free b32 writes, uniform b64 reads)

template <int N>
__global__ __launch_bounds__(256, 4) void dwt2_level(
    const float* __restrict__ src,
    float* __restrict__ aa, float* __restrict__ da,
    float* __restrict__ ad, float* __restrict__ dd)
{
    constexpr float SQ2 = 1.41421356237309504880f;
    constexpr float c_lo[12] = {
        -20.f * SQ2 / 2048.f,  60.f * SQ2 / 2048.f,   76.f * SQ2 / 2048.f,
        -388.f * SQ2 / 2048.f, -104.f * SQ2 / 2048.f, 1400.f * SQ2 / 2048.f,
        1400.f * SQ2 / 2048.f, -104.f * SQ2 / 2048.f, -388.f * SQ2 / 2048.f,
        76.f * SQ2 / 2048.f,   60.f * SQ2 / 2048.f,   -20.f * SQ2 / 2048.f };
    constexpr float c_hi4[4] = { -SQ2 / 8.f, 3.f * SQ2 / 8.f, -3.f * SQ2 / 8.f, SQ2 / 8.f };

    constexpr int h    = N >> 1;
    constexpr int mask = N - 1;

    const int bc  = blockIdx.z;
    const int j0  = blockIdx.x * OW;
    const int i0  = blockIdx.y * ROWS_PB;
    const int tid = threadIdx.x;

    __shared__ float s_in[IN_ROWS * SPITCH];   // 14.1 KB
    __shared__ float s_loT[OW * TRS];          // 5.4 KB
    __shared__ float s_hiT[OW * TRS];          // 5.4 KB   (total 24.9 KB -> 6 blocks/CU)

    const float* img = src + (unsigned)bc * (unsigned)(N * N);
    const int c0 = 2 * j0 - 12;   // quad-aligned col base (multiple of 4)

    // Staged quad q of step s: always a contiguous, 16B-aligned global read.
    // (c0 % 4 == 0 so a wrapped quad never straddles the image edge.)
    auto ldq = [&](int s, int q) -> float4 {
        const int r  = q / QPR;
        const int c4 = q - r * QPR;
        const int gr = (2 * (i0 + OHS * s) - 10 + r) & mask;
        const int gc = (c0 + 4 * c4) & mask;
        return *(const float4*)(img + (unsigned)(gr * N + gc));
    };
    auto stq = [&](int q, float4 v) {
        const int r  = q / QPR;
        const int c4 = q - r * QPR;
        *(float4*)&s_in[r * SPITCH + 4 * c4] = v;
    };

    const bool has4 = tid < (NQ - 768);   // 72 threads stage a 4th quad

    // ---- prologue: stage step 0 ----
    float4 pf0 = ldq(0, tid);
    float4 pf1 = ldq(0, tid + 256);
    float4 pf2 = ldq(0, tid + 512);
    float4 pf3 = make_float4(0.f, 0.f, 0.f, 0.f);
    if (has4) pf3 = ldq(0, tid + 768);
    stq(tid, pf0);
    stq(tid + 256, pf1);
    stq(tid + 512, pf2);
    if (has4) stq(tid + 768, pf3);

    for (int s = 0; s < NSTEP; ++s) {
        __syncthreads();                  // s_in for step s visible to all waves

        // issue next step's loads now; they stay in flight across both phases
        if (s + 1 < NSTEP) {
            pf0 = ldq(s + 1, tid);
            pf1 = ldq(s + 1, tid + 256);
            pf2 = ldq(s + 1, tid + 512);
            if (has4) pf3 = ldq(s + 1, tid + 768);
        }

        // ---- phase 1: row pass. 168 tasks, 8 output cols each ----
        if (tid < IN_ROWS * (OW / 8)) {
            const int m = tid & 3;
            const int r = tid >> 2;
            const float* p = &s_in[r * SPITCH + 16 * m];
            float v[28];
            #pragma unroll
            for (int q = 0; q < 7; ++q)
                *(float4*)&v[4 * q] = *(const float4*)&p[4 * q];
            #pragma unroll
            for (int d = 0; d < 8; ++d) {
                float lo = 0.f, hi = 0.f;
                #pragma unroll
                for (int jc = 0; jc < 12; ++jc)
                    lo += c_lo[jc] * v[2 * d + 13 - jc];
                #pragma unroll
                for (int k = 0; k < 4; ++k)
                    hi += c_hi4[k] * v[2 * d + 9 - k];
                s_loT[(8 * m + d) * TRS + r] = lo;
                s_hiT[(8 * m + d) * TRS + r] = hi;
            }
        }
        __syncthreads();                  // s_loT visible; s_in fully consumed

        // ---- phase 2: column pass. thread (tx,ty) -> col j0+tx, rows 2ty, 2ty+1 ----
        {
            const int tx = tid & 31;
            const int ty = tid >> 5;      // 0..7
            float l[14], hh[14];
            #pragma unroll
            for (int e = 0; e < 7; ++e) {
                *(float2*)&l[2 * e]  = *(const float2*)&s_loT[tx * TRS + 4 * ty + 2 * e];
                *(float2*)&hh[2 * e] = *(const float2*)&s_hiT[tx * TRS + 4 * ty + 2 * e];
            }
            float vaa0 = 0.f, vaa1 = 0.f, vad0 = 0.f, vad1 = 0.f;
            #pragma unroll
            for (int jr = 0; jr < 12; ++jr) {
                vaa0 += c_lo[jr] * l[11 - jr];
                vaa1 += c_lo[jr] * l[13 - jr];
                vad0 += c_lo[jr] * hh[11 - jr];
                vad1 += c_lo[jr] * hh[13 - jr];
            }
            float vda0 = 0.f, vda1 = 0.f, vdd0 = 0.f, vdd1 = 0.f;
            #pragma unroll
            for (int k = 0; k < 4; ++k) {
                vda0 += c_hi4[k] * l[7 - k];
                vda1 += c_hi4[k] * l[9 - k];
                vdd0 += c_hi4[k] * hh[7 - k];
                vdd1 += c_hi4[k] * hh[9 - k];
            }
            const int orow = i0 + OHS * s + 2 * ty;
            const unsigned ob = (unsigned)((bc * h + orow) * h + j0 + tx);
            aa[ob] = vaa0;  aa[ob + h] = vaa1;
            da[ob] = vda0;  da[ob + h] = vda1;
            ad[ob] = vad0;  ad[ob + h] = vad1;
            dd[ob] = vdd0;  dd[ob + h] = vdd1;
        }

        // ---- write prefetched quads into s_in for step s+1 ----
        if (s + 1 < NSTEP) {
            stq(tid, pf0);
            stq(tid + 256, pf1);
            stq(tid + 512, pf2);
            if (has4) stq(tid + 768, pf3);
        }
    }
}

extern "C" void kernel_launch(void* const* d_in, const int* in_sizes, int n_in,
                              void* d_out, int out_size, void* d_ws, size_t ws_size,
                              hipStream_t stream) {
    const float* x = (const float*)d_in[0];
    float* out = (float*)d_out;
    float* ws  = (float*)d_ws;

    // 24 independent N x N images (8 batch x 3 channels).
    const size_t s512 = (size_t)24 * 512 * 512;
    const size_t s256 = (size_t)24 * 256 * 256;
    const size_t s128 = (size_t)24 * 128 * 128;

    // d_out layout (return order): a | h3(da,ad,dd) | h2(...) | h1(...)
    float* a_out = out;
    float* h3 = out + s128;
    float* h2 = out + 4 * s128;
    float* h1 = out + 4 * s128 + 3 * s256;

    float* aa1 = ws;          // 512^2 intermediate
    float* aa2 = ws + s512;   // 256^2 intermediate
    (void)in_sizes; (void)n_in; (void)out_size; (void)ws_size;

    dim3 blk(256, 1, 1);
    // level 1: 1024 -> 512
    dwt2_level<1024><<<dim3(512 / OW, 512 / ROWS_PB, 24), blk, 0, stream>>>(
        x, aa1, h1, h1 + s512, h1 + 2 * s512);
    // level 2: 512 -> 256
    dwt2_level<512><<<dim3(256 / OW, 256 / ROWS_PB, 24), blk, 0, stream>>>(
        aa1, aa2, h2, h2 + s256, h2 + 2 * s256);
    // level 3: 256 -> 128
    dwt2_level<256><<<dim3(128 / OW, 128 / ROWS_PB, 24), blk, 0, stream>>>(
        aa2, a_out, h3, h3 + s128, h3 + 2 * s128);
}